// Round 1
// baseline (872.957 us; speedup 1.0000x reference)
//
#include <hip/hip_runtime.h>

// TensorProduct (e3nn-style): MUL=32, DIMS=(1,3,5), Z=400000, 15 CG paths.
//
// Restructure: paths have unique (i1,i2,i3), so the op factors as
//   W[z][i][k] = sum_j C[i][j][k] * x2[z][j]      (615 FMAs per z, shared)
//   out[z,u,k] = sum_i x1[z,u,i] * W[z][i][k]     (81 FMAs per thread)
// where C is the fixed 9x9x9 scatter of cg (<=1 path per (blk_i,blk_j,blk_k)).
// This removes the ~615 wave-uniform s_load_dword cg coefficients per wave
// (the scalar-pipe serialization that held the old kernel at ~19% HBM) and
// cuts per-thread FMAs ~8x. Target: HBM-bound ~936 MB -> ~150-200 us.

namespace {
constexpr int kZ     = 400000;
constexpr int kZTile = 8;                 // z's per block; 400000 % 8 == 0
constexpr int kBlock = 256;               // 8 z * 32 u

// Compile-time table: for each (i,k) in 9x9 and each input block i2 in 0..2,
// the cg base offset (p*125 + li*25 + lk) or -1 if the path doesn't exist.
// The j-sum within block i2 walks cg at stride 5 (lj*5).
struct Tab { int v[81 * 3]; };

constexpr int blk_of(int g) { return (g >= 1) + (g >= 4); }   // 0|123|45678

constexpr Tab make_tab() {
    Tab t{};
    const int ins[15][3] = {
        {0,0,0},{0,1,1},{0,2,2},{1,0,1},{1,1,0},{1,1,1},{1,1,2},{1,2,1},
        {1,2,2},{2,0,2},{2,1,1},{2,1,2},{2,2,0},{2,2,1},{2,2,2}};
    int pidx[27];
    for (int x = 0; x < 27; ++x) pidx[x] = -1;
    for (int p = 0; p < 15; ++p)
        pidx[ins[p][0] * 9 + ins[p][1] * 3 + ins[p][2]] = p;
    const int goff[3] = {0, 1, 4};
    for (int i = 0; i < 9; ++i)
        for (int k = 0; k < 9; ++k)
            for (int i2 = 0; i2 < 3; ++i2) {
                const int bi = blk_of(i), bk = blk_of(k);
                const int p  = pidx[bi * 9 + i2 * 3 + bk];
                t.v[(i * 9 + k) * 3 + i2] =
                    (p < 0) ? -1
                            : p * 125 + (i - goff[bi]) * 25 + (k - goff[bk]);
            }
    return t;
}

__device__ const Tab kTab = make_tab();
}

__global__ __launch_bounds__(kBlock) void tp_kernel(
    const float* __restrict__ x1,
    const float* __restrict__ x2,
    const float* __restrict__ cg,
    float* __restrict__ out)
{
    __shared__ float x2s[kZTile * 9];      // staged x2 tile (72 floats)
    __shared__ float Ws[kZTile][9][12];    // W rows padded to 12 -> 16B-aligned
                                           // ds_read_b128; z-stride 432B keeps
                                           // the two half-wave broadcasts on
                                           // disjoint banks.

    const int tid = threadIdx.x;
    const int u   = tid & 31;
    const int zl  = tid >> 5;
    const int z   = blockIdx.x * kZTile + zl;

    // Issue the x1 loads first: HBM latency hides under phase 1.
    // Row layout: [irrep0: 32x1][irrep1: 32x3][irrep2: 32x5], elem (u,m) at
    // off + u*d + m. Per-lane scalar dwords, contiguous across the 32 lanes.
    const float* __restrict__ x1r = x1 + (size_t)z * 288;
    float a[9];
    a[0] = x1r[u];
#pragma unroll
    for (int m = 0; m < 3; ++m) a[1 + m] = x1r[32 + u * 3 + m];
#pragma unroll
    for (int m = 0; m < 5; ++m) a[4 + m] = x1r[128 + u * 5 + m];

    // Stage the 72-float x2 tile (fully coalesced).
    if (tid < kZTile * 9) x2s[tid] = x2[(size_t)blockIdx.x * kZTile * 9 + tid];
    __syncthreads();

    // ---- Phase 1: W[zl][i][k] = sum_j C[i][j][k] * x2[z][j] ----
    // 32 lanes per z cover the 81 (i,k) entries in <=3 rounds. cg reads are
    // per-lane vector loads into a 7.5 KB L1-resident buffer.
    float xb[9];
#pragma unroll
    for (int j = 0; j < 9; ++j) xb[j] = x2s[zl * 9 + j];

    for (int r = u; r < 81; r += 32) {
        const int i = r / 9;
        const int k = r - i * 9;
        const int* tp = &kTab.v[r * 3];
        float w = 0.0f;
        {
            const int b = tp[0];                 // i2=0, d2=1, j0=0
            if (b >= 0) w = fmaf(cg[b], xb[0], w);
        }
        {
            const int b = tp[1];                 // i2=1, d2=3, j0=1
            if (b >= 0) {
#pragma unroll
                for (int lj = 0; lj < 3; ++lj)
                    w = fmaf(cg[b + 5 * lj], xb[1 + lj], w);
            }
        }
        {
            const int b = tp[2];                 // i2=2, d2=5, j0=4
            if (b >= 0) {
#pragma unroll
                for (int lj = 0; lj < 5; ++lj)
                    w = fmaf(cg[b + 5 * lj], xb[4 + lj], w);
            }
        }
        Ws[zl][i][k] = w;
    }
    __syncthreads();

    // ---- Phase 2: o[k] = sum_i a[i] * W[i][k] (81 FMAs) ----
    // Ws row reads compile to ds_read_b128 x2 + b32, broadcast per half-wave.
    float o[9];
#pragma unroll
    for (int k = 0; k < 9; ++k) o[k] = 0.0f;
#pragma unroll
    for (int i = 0; i < 9; ++i) {
#pragma unroll
        for (int k = 0; k < 9; ++k)
            o[k] = fmaf(a[i], Ws[zl][i][k], o[k]);
    }

    float* __restrict__ outr = out + (size_t)z * 288;
    outr[u] = o[0];
#pragma unroll
    for (int k = 0; k < 3; ++k) outr[32 + u * 3 + k] = o[1 + k];
#pragma unroll
    for (int k = 0; k < 5; ++k) outr[128 + u * 5 + k] = o[4 + k];
}

extern "C" void kernel_launch(void* const* d_in, const int* in_sizes, int n_in,
                              void* d_out, int out_size, void* d_ws, size_t ws_size,
                              hipStream_t stream) {
    const float* x1 = (const float*)d_in[0];
    const float* x2 = (const float*)d_in[1];
    const float* cg = (const float*)d_in[2];
    float* out = (float*)d_out;

    const int grid = kZ / kZTile;   // 50000 blocks, exact
    tp_kernel<<<grid, kBlock, 0, stream>>>(x1, x2, cg, out);
}